// Round 1
// 17841.251 us; speedup vs baseline: 1.7329x; 1.7329x over previous
//
#include <hip/hip_runtime.h>
#include <hip/hip_bf16.h>

// STN_RNN: B=32, T=4096, IN=1, H=512, gates=2048, k=0.5 blend.
// R5: register-resident bf16-packed W_hh. 256 WGs = 32 batches x 8 slices,
// 512 threads/WG (8 waves/CU, 2 waves/SIMD). Each thread holds its
// 4 cols x 64 k = 256 weights as 128 packed-bf16 u32 VGPRs, loaded once.
// Inner dot loop is pure VALU (unpack + fma) + broadcast LDS reads of h.
// Cross-WG h exchange: unchanged relaxed agent-scope atomic protocol
// (h double-buffer + per-batch monotonic counter, wave0 s_waitcnt drain).

#define NBATCH 32
#define NT     4096
#define NH     512
#define UNITS  64

// ws byte offsets
#define FLAG_OFF  0u
#define CTR_OFF   64u        // 32 counters, stride 16 u32 (64B)
#define BIAS_OFF  4096u      // 2048 f32
#define WIH_OFF   12288u     // 2048 f32
#define XF_OFF    20480u     // 131072 f32 = 512 KiB
#define HBUF_OFF  544768u    // 2*32*512 f32 = 128 KiB
#define WP_OFF    675840u    // 8 slices x 32 r4 x 512 tid x 4 u32 = 2 MiB

__device__ __forceinline__ float bf2f(unsigned short u) {
    union { unsigned int i; float f; } v; v.i = ((unsigned int)u) << 16; return v.f;
}
__device__ __forceinline__ unsigned short f2bf_rne(float f) {
    union { unsigned int i; float f; } v; v.f = f;
    return (unsigned short)((v.i + 0x7fffu + ((v.i >> 16) & 1u)) >> 16);
}
__device__ __forceinline__ float lo_bf(unsigned int u) {
    union { unsigned int i; float f; } v; v.i = u << 16; return v.f;
}
__device__ __forceinline__ float hi_bf(unsigned int u) {
    union { unsigned int i; float f; } v; v.i = u & 0xffff0000u; return v.f;
}
__device__ __forceinline__ float sigm(float x) {
    return 1.0f / (1.0f + __expf(-x));
}
__device__ __forceinline__ float tanh_fast(float x) {
    float e = __expf(-2.0f * fabsf(x));
    float r = (1.0f - e) / (1.0f + e);
    return copysignf(r, x);
}
// col = wg*256 + (gate*64 + u)  ->  row = gate*512 + wg*64 + u
__device__ __forceinline__ int col2row(int col) {
    int wg = col >> 8, r = col & 255, g = (r >> 6) & 3, u = r & 63;
    return g * 512 + wg * 64 + u;
}

// ---- dtype detect (bf16 vs f32) + zero counters ----
__global__ void prep_detect(const unsigned short* __restrict__ wih_u,
                            int* __restrict__ flagp,
                            unsigned int* __restrict__ ctr) {
    __shared__ int cnt;
    if (threadIdx.x == 0) cnt = 0;
    __syncthreads();
    int local = 0;
    for (int i = threadIdx.x; i < 1024; i += 256) {
        float v = bf2f(wih_u[2 * i]);
        if (fabsf(v) <= 0.0625f) local++;
    }
    atomicAdd(&cnt, local);
    __syncthreads();
    if (threadIdx.x == 0) *flagp = (cnt >= 1000) ? 1 : 0;
    if (threadIdx.x < 32) ctr[threadIdx.x * 16] = 0u;
}

// ---- build packed per-thread weight image WP, bias, W_ih, x ----
// WP dword index = wg*65536 + r4*2048 + tid*4 + j   (r = r4*4+j, c=r>>5, k2=r&31)
// value = pack_bf16( W[row(col)][k0], W[row(col)][k0+1] ), col=wg*256+jq*4+c,
// k0 = ks*64 + 2*k2, jq=tid&63, ks=tid>>6.
__global__ void prep_conv(const void* __restrict__ x,
                          const void* __restrict__ Wih,
                          const void* __restrict__ Whh,
                          const void* __restrict__ bih,
                          const void* __restrict__ bhh,
                          const int* __restrict__ flagp,
                          unsigned int* __restrict__ WP,
                          float* __restrict__ bias_p,
                          float* __restrict__ wih_p,
                          float* __restrict__ Xf) {
    int idx = blockIdx.x * blockDim.x + threadIdx.x;   // 524288
    int isbf = *flagp;

    {
        int wg  = idx >> 16;
        int rem = idx & 65535;
        int r4  = rem >> 11;
        int tid = (rem >> 2) & 511;
        int j   = rem & 3;
        int r   = r4 * 4 + j;
        int c   = r >> 5;
        int k2  = r & 31;
        int jq  = tid & 63;
        int ks  = tid >> 6;
        int col = wg * 256 + jq * 4 + c;
        int row = col2row(col);
        int k0  = ks * 64 + 2 * k2;
        unsigned short lo, hi;
        if (isbf) {
            lo = ((const unsigned short*)Whh)[(size_t)row * 512 + k0];
            hi = ((const unsigned short*)Whh)[(size_t)row * 512 + k0 + 1];
        } else {
            lo = f2bf_rne(((const float*)Whh)[(size_t)row * 512 + k0]);
            hi = f2bf_rne(((const float*)Whh)[(size_t)row * 512 + k0 + 1]);
        }
        WP[idx] = (unsigned int)lo | ((unsigned int)hi << 16);
    }

    if (idx < 2048) {
        int col = idx;
        int row = col2row(col);
        float bi, bh, wi;
        if (isbf) {
            bi = bf2f(((const unsigned short*)bih)[row]);
            bh = bf2f(((const unsigned short*)bhh)[row]);
            wi = bf2f(((const unsigned short*)Wih)[row]);
        } else {
            bi = ((const float*)bih)[row];
            bh = ((const float*)bhh)[row];
            wi = ((const float*)Wih)[row];
        }
        bias_p[col] = bi + bh;
        wih_p[col]  = wi;
    }
    if (idx < NBATCH * NT) {
        Xf[idx] = isbf ? bf2f(((const unsigned short*)x)[idx])
                       : ((const float*)x)[idx];
    }
}

__global__ void __launch_bounds__(512, 2) rnn_kernel(
    const float* __restrict__ Xf,
    const unsigned int* __restrict__ WP,
    const float* __restrict__ bias_p,
    const float* __restrict__ wih_p,
    float* __restrict__ hbuf,
    unsigned int* __restrict__ ctr,
    const int* __restrict__ flagp,
    void* __restrict__ out)
{
    const int tid = threadIdx.x;
    const int bid = blockIdx.x;
    const int b   = bid & 31;
    const int wg  = bid >> 5;
    const int isbf = *flagp;

    __shared__ float hsh[512];
    __shared__ float parts[8][256];
    __shared__ float gates[256];
    __shared__ float cst[UNITS];
    __shared__ float hst[UNITS];

    if (tid < UNITS) { cst[tid] = 0.0f; hst[tid] = 0.0f; }

    const int jq = tid & 63;
    const int ks = tid >> 6;

    // ---- load register-resident packed weights: 128 u32 = 256 bf16 ----
    unsigned int w[128];
    {
        const uint4* wp = (const uint4*)WP + (size_t)wg * 16384 + tid;
        #pragma unroll
        for (int r4 = 0; r4 < 32; ++r4) {
            uint4 v = wp[(size_t)r4 * 512];
            w[r4 * 4 + 0] = v.x;
            w[r4 * 4 + 1] = v.y;
            w[r4 * 4 + 2] = v.z;
            w[r4 * 4 + 3] = v.w;
        }
    }

    float biasr = 0.0f, wihr = 0.0f;
    if (tid < 256) {
        biasr = bias_p[wg * 256 + tid];
        wihr  = wih_p[wg * 256 + tid];
    }

    unsigned int* ctrb = ctr + b * 16;   // one cacheline per batch
    unsigned short* outb_u = (unsigned short*)out + (size_t)b * NT * NH;
    float*          outb_f = (float*)out + (size_t)b * NT * NH;

    unsigned int broken = 0;

    for (int t = 0; t < NT; ++t) {
        // ---- acquire h_t ----
        if (t == 0) {
            hsh[tid] = 0.0f;
        } else {
            if (tid == 0 && !broken) {
                unsigned int target = 8u * (unsigned int)t;
                int g = 0;
                while (__hip_atomic_load(ctrb, __ATOMIC_RELAXED,
                                         __HIP_MEMORY_SCOPE_AGENT) < target) {
                    __builtin_amdgcn_s_sleep(1);
                    if (++g > 16000000) { broken = 1; break; }
                }
            }
            __syncthreads();
            __atomic_signal_fence(__ATOMIC_SEQ_CST);
            // coherent (cache-bypass) load: 1 float/thread, 512 threads
            const float* hin = hbuf + (((t & 1) * NBATCH + b) << 9);
            hsh[tid] = __hip_atomic_load(hin + tid, __ATOMIC_RELAXED,
                                         __HIP_MEMORY_SCOPE_AGENT);
        }
        __syncthreads();

        // ---- gate dots from registers: 4 cols x 64 k per thread ----
        float a0 = 0.f, a1 = 0.f, a2 = 0.f, a3 = 0.f;
        float c0 = 0.f, c1 = 0.f, c2 = 0.f, c3 = 0.f;
        const float* hq = hsh + ks * 64;
        #pragma unroll
        for (int k2 = 0; k2 < 32; ++k2) {
            float h0 = hq[2 * k2];
            float h1 = hq[2 * k2 + 1];
            unsigned int u0 = w[k2];
            unsigned int u1 = w[32 + k2];
            unsigned int u2 = w[64 + k2];
            unsigned int u3 = w[96 + k2];
            a0 = fmaf(h0, lo_bf(u0), a0);  c0 = fmaf(h1, hi_bf(u0), c0);
            a1 = fmaf(h0, lo_bf(u1), a1);  c1 = fmaf(h1, hi_bf(u1), c1);
            a2 = fmaf(h0, lo_bf(u2), a2);  c2 = fmaf(h1, hi_bf(u2), c2);
            a3 = fmaf(h0, lo_bf(u3), a3);  c3 = fmaf(h1, hi_bf(u3), c3);
        }
        a0 += c0; a1 += c1; a2 += c2; a3 += c3;
        *(float4*)&parts[ks][jq * 4] = make_float4(a0, a1, a2, a3);
        __syncthreads();

        // ---- reduce 8 k-slices + bias + x term (tid<256) ----
        float xt = Xf[b * NT + t];
        if (tid < 256) {
            float g = parts[0][tid] + parts[1][tid] + parts[2][tid] + parts[3][tid]
                    + parts[4][tid] + parts[5][tid] + parts[6][tid] + parts[7][tid]
                    + biasr + xt * wihr;
            gates[tid] = g;
        }
        __syncthreads();

        // ---- LSTM cell + STN blend (wave 0 only: tid<64) ----
        if (tid < UNITS) {
            float ig = sigm(gates[tid]);
            float fg = sigm(gates[64 + tid]);
            float gg = tanh_fast(gates[128 + tid]);
            float og = sigm(gates[192 + tid]);
            float cold = cst[tid], hold = hst[tid];
            float cnew = fg * cold + ig * gg;
            float hnew = og * tanh_fast(cnew);
            float cb = 0.5f * (cold + cnew);
            float hb = 0.5f * (hold + hnew);
            cst[tid] = cb; hst[tid] = hb;
            // coherent (cache-bypass) h publish
            float* hout = hbuf + ((((t + 1) & 1) * NBATCH + b) << 9);
            __hip_atomic_store(&hout[wg * 64 + tid], hb, __ATOMIC_RELAXED,
                               __HIP_MEMORY_SCOPE_AGENT);
            if (isbf) outb_u[(size_t)t * NH + wg * 64 + tid] = f2bf_rne(hb);
            else      outb_f[(size_t)t * NH + wg * 64 + tid] = hb;
        }
        // wave 0: drain h-stores, then post. (s_waitcnt is per-wave; the
        // h-stores and this post are both in wave 0.)
        __atomic_signal_fence(__ATOMIC_SEQ_CST);
        if (tid < 64) {
            __builtin_amdgcn_s_waitcnt(0);
            if (tid == 0)
                __hip_atomic_fetch_add(ctrb, 1u, __ATOMIC_RELAXED,
                                       __HIP_MEMORY_SCOPE_AGENT);
        }
        __syncthreads();   // guards hsh/parts/gates reuse next iter
    }

    // ---- final_state [h | c] ----
    if (tid < UNITS) {
        size_t fsbase = (size_t)NBATCH * NT * NH + (size_t)b * (2 * NH);
        if (isbf) {
            ((unsigned short*)out)[fsbase + wg * 64 + tid]       = f2bf_rne(hst[tid]);
            ((unsigned short*)out)[fsbase + 512 + wg * 64 + tid] = f2bf_rne(cst[tid]);
        } else {
            ((float*)out)[fsbase + wg * 64 + tid]       = hst[tid];
            ((float*)out)[fsbase + 512 + wg * 64 + tid] = cst[tid];
        }
    }
}

extern "C" void kernel_launch(void* const* d_in, const int* in_sizes, int n_in,
                              void* d_out, int out_size, void* d_ws, size_t ws_size,
                              hipStream_t stream) {
    const void* x   = d_in[0];
    const void* Wih = d_in[1];
    const void* Whh = d_in[2];
    const void* bih = d_in[3];
    const void* bhh = d_in[4];

    char* ws = (char*)d_ws;
    int* flagp          = (int*)(ws + FLAG_OFF);
    unsigned int* ctrp  = (unsigned int*)(ws + CTR_OFF);
    float* bias_p       = (float*)(ws + BIAS_OFF);
    float* wih_p        = (float*)(ws + WIH_OFF);
    float* Xf           = (float*)(ws + XF_OFF);
    float* hbuf         = (float*)(ws + HBUF_OFF);
    unsigned int* WP    = (unsigned int*)(ws + WP_OFF);

    prep_detect<<<1, 256, 0, stream>>>((const unsigned short*)Wih, flagp, ctrp);
    prep_conv<<<2048, 256, 0, stream>>>(x, Wih, Whh, bih, bhh, flagp,
                                        WP, bias_p, wih_p, Xf);
    rnn_kernel<<<256, 512, 0, stream>>>(Xf, WP, bias_p, wih_p, hbuf, ctrp,
                                        flagp, d_out);
}

// Round 3
// 15859.596 us; speedup vs baseline: 1.9495x; 1.1249x over previous
//
#include <hip/hip_runtime.h>
#include <hip/hip_bf16.h>

// STN_RNN: B=32, T=4096, IN=1, H=512, gates=2048, k=0.5 blend.
// R7 = R6 with the hbuf-zeroing overrun fixed (was zeroing 131072 dwords,
// hbuf is only 65536 dwords -> the excess wiped wg0's weight slice in WP).
// Protocol: single-leg h exchange via data-carrying tags. Each published h
// is one 8B atomic {u32 tag=t | f32 h}: the store itself is the signal
// (8B aligned store is tear-free), replacing the old waitcnt -> fetch_add ->
// counter-poll -> h-load chain (~4 coherence round trips) with one.
// Parity double buffer (t&1) is ABA-safe: slot reuse (tag t -> t+2) requires
// two full batch-wide consume/publish rounds, and barrier A orders every
// consumer's read before its WG's next publish.
// Weights register-resident bf16-packed (128 u32/thread); x row in LDS;
// 3 barriers/step.

#define NBATCH 32
#define NT     4096
#define NH     512
#define UNITS  64

// ws byte offsets
#define FLAG_OFF  0u
#define BIAS_OFF  4096u      // 2048 f32
#define WIH_OFF   12288u     // 2048 f32
#define XF_OFF    20480u     // 131072 f32 = 512 KiB
#define HBUF_OFF  544768u    // 2*32*512 x 8B tagged = 256 KiB = 65536 dwords
#define WP_OFF    806912u    // 8 slices x 32 r4 x 512 tid x 4 u32 = 2 MiB

#define HBUF_DWORDS 65536

__device__ __forceinline__ float bf2f(unsigned short u) {
    union { unsigned int i; float f; } v; v.i = ((unsigned int)u) << 16; return v.f;
}
__device__ __forceinline__ unsigned short f2bf_rne(float f) {
    union { unsigned int i; float f; } v; v.f = f;
    return (unsigned short)((v.i + 0x7fffu + ((v.i >> 16) & 1u)) >> 16);
}
__device__ __forceinline__ float lo_bf(unsigned int u) {
    union { unsigned int i; float f; } v; v.i = u << 16; return v.f;
}
__device__ __forceinline__ float hi_bf(unsigned int u) {
    union { unsigned int i; float f; } v; v.i = u & 0xffff0000u; return v.f;
}
__device__ __forceinline__ float sigm(float x) {
    return 1.0f / (1.0f + __expf(-x));
}
__device__ __forceinline__ float tanh_fast(float x) {
    float e = __expf(-2.0f * fabsf(x));
    float r = (1.0f - e) / (1.0f + e);
    return copysignf(r, x);
}
// col = wg*256 + (gate*64 + u)  ->  row = gate*512 + wg*64 + u
__device__ __forceinline__ int col2row(int col) {
    int wg = col >> 8, r = col & 255, g = (r >> 6) & 3, u = r & 63;
    return g * 512 + wg * 64 + u;
}

// ---- dtype detect (bf16 vs f32) ----
__global__ void prep_detect(const unsigned short* __restrict__ wih_u,
                            int* __restrict__ flagp) {
    __shared__ int cnt;
    if (threadIdx.x == 0) cnt = 0;
    __syncthreads();
    int local = 0;
    for (int i = threadIdx.x; i < 1024; i += 256) {
        float v = bf2f(wih_u[2 * i]);
        if (fabsf(v) <= 0.0625f) local++;
    }
    atomicAdd(&cnt, local);
    __syncthreads();
    if (threadIdx.x == 0) *flagp = (cnt >= 1000) ? 1 : 0;
}

// ---- build packed per-thread weight image WP, bias, W_ih, x; zero hbuf ----
// WP dword index = wg*65536 + r4*2048 + tid*4 + j   (r = r4*4+j, c=r>>5, k2=r&31)
// value = pack_bf16( W[row(col)][k0], W[row(col)][k0+1] ), col=wg*256+jq*4+c,
// k0 = ks*64 + 2*k2, jq=tid&63, ks=tid>>6.
__global__ void prep_conv(const void* __restrict__ x,
                          const void* __restrict__ Wih,
                          const void* __restrict__ Whh,
                          const void* __restrict__ bih,
                          const void* __restrict__ bhh,
                          const int* __restrict__ flagp,
                          unsigned int* __restrict__ WP,
                          float* __restrict__ bias_p,
                          float* __restrict__ wih_p,
                          float* __restrict__ Xf,
                          unsigned int* __restrict__ hbuf_z) {
    int idx = blockIdx.x * blockDim.x + threadIdx.x;   // 524288
    int isbf = *flagp;

    {
        int wg  = idx >> 16;
        int rem = idx & 65535;
        int r4  = rem >> 11;
        int tid = (rem >> 2) & 511;
        int j   = rem & 3;
        int r   = r4 * 4 + j;
        int c   = r >> 5;
        int k2  = r & 31;
        int jq  = tid & 63;
        int ks  = tid >> 6;
        int col = wg * 256 + jq * 4 + c;
        int row = col2row(col);
        int k0  = ks * 64 + 2 * k2;
        unsigned short lo, hi;
        if (isbf) {
            lo = ((const unsigned short*)Whh)[(size_t)row * 512 + k0];
            hi = ((const unsigned short*)Whh)[(size_t)row * 512 + k0 + 1];
        } else {
            lo = f2bf_rne(((const float*)Whh)[(size_t)row * 512 + k0]);
            hi = f2bf_rne(((const float*)Whh)[(size_t)row * 512 + k0 + 1]);
        }
        WP[idx] = (unsigned int)lo | ((unsigned int)hi << 16);
    }

    // zero the tagged h double-buffer (exactly HBUF_DWORDS dwords!) so
    // stale tags from a previous launch can never match.
    if (idx < HBUF_DWORDS) hbuf_z[idx] = 0u;

    if (idx < 2048) {
        int col = idx;
        int row = col2row(col);
        float bi, bh, wi;
        if (isbf) {
            bi = bf2f(((const unsigned short*)bih)[row]);
            bh = bf2f(((const unsigned short*)bhh)[row]);
            wi = bf2f(((const unsigned short*)Wih)[row]);
        } else {
            bi = ((const float*)bih)[row];
            bh = ((const float*)bhh)[row];
            wi = ((const float*)Wih)[row];
        }
        bias_p[col] = bi + bh;
        wih_p[col]  = wi;
    }
    if (idx < NBATCH * NT) {
        Xf[idx] = isbf ? bf2f(((const unsigned short*)x)[idx])
                       : ((const float*)x)[idx];
    }
}

__global__ void __launch_bounds__(512, 2) rnn_kernel(
    const float* __restrict__ Xf,
    const unsigned int* __restrict__ WP,
    const float* __restrict__ bias_p,
    const float* __restrict__ wih_p,
    unsigned long long* __restrict__ hbuf,
    const int* __restrict__ flagp,
    void* __restrict__ out)
{
    const int tid = threadIdx.x;
    const int bid = blockIdx.x;
    const int b   = bid & 31;
    const int wg  = bid >> 5;
    const int isbf = *flagp;

    __shared__ float hsh[512];
    __shared__ float xsh[NT];          // 16 KiB: whole x row for this batch
    __shared__ float parts[8][256];
    __shared__ float gates[256];
    __shared__ float cst[UNITS];
    __shared__ float hst[UNITS];

    if (tid < UNITS) { cst[tid] = 0.0f; hst[tid] = 0.0f; }

    const int jq = tid & 63;
    const int ks = tid >> 6;

    // ---- stage x row in LDS (synced by barrier A of t=0) ----
    for (int i = tid; i < NT; i += 512) xsh[i] = Xf[(size_t)b * NT + i];

    // ---- load register-resident packed weights: 128 u32 = 256 bf16 ----
    unsigned int w[128];
    {
        const uint4* wp = (const uint4*)WP + (size_t)wg * 16384 + tid;
        #pragma unroll
        for (int r4 = 0; r4 < 32; ++r4) {
            uint4 v = wp[(size_t)r4 * 512];
            w[r4 * 4 + 0] = v.x;
            w[r4 * 4 + 1] = v.y;
            w[r4 * 4 + 2] = v.z;
            w[r4 * 4 + 3] = v.w;
        }
    }

    float biasr = 0.0f, wihr = 0.0f;
    if (tid < 256) {
        biasr = bias_p[wg * 256 + tid];
        wihr  = wih_p[wg * 256 + tid];
    }

    unsigned short* outb_u = (unsigned short*)out + (size_t)b * NT * NH;
    float*          outb_f = (float*)out + (size_t)b * NT * NH;

    unsigned int broken = 0;

    for (int t = 0; t < NT; ++t) {
        // ---- acquire h_t: every thread polls its own tagged 8B word ----
        if (t == 0) {
            hsh[tid] = 0.0f;
        } else {
            const unsigned long long* hin =
                hbuf + (((t & 1) * NBATCH + b) << 9);
            unsigned long long v = 0;
            if (!broken) {
                int g = 0;
                for (;;) {
                    v = __hip_atomic_load(hin + tid, __ATOMIC_RELAXED,
                                          __HIP_MEMORY_SCOPE_AGENT);
                    if ((unsigned int)(v >> 32) == (unsigned int)t) break;
                    __builtin_amdgcn_s_sleep(1);
                    if (++g > 16000000) { broken = 1; v = 0; break; }
                }
            }
            union { unsigned int u; float f; } cv; cv.u = (unsigned int)v;
            hsh[tid] = cv.f;
        }
        __syncthreads();                       // barrier A

        // ---- gate dots from registers: 4 cols x 64 k per thread ----
        float a0 = 0.f, a1 = 0.f, a2 = 0.f, a3 = 0.f;
        float c0 = 0.f, c1 = 0.f, c2 = 0.f, c3 = 0.f;
        const float* hq = hsh + ks * 64;
        #pragma unroll
        for (int k2 = 0; k2 < 32; ++k2) {
            float h0 = hq[2 * k2];
            float h1 = hq[2 * k2 + 1];
            unsigned int u0 = w[k2];
            unsigned int u1 = w[32 + k2];
            unsigned int u2 = w[64 + k2];
            unsigned int u3 = w[96 + k2];
            a0 = fmaf(h0, lo_bf(u0), a0);  c0 = fmaf(h1, hi_bf(u0), c0);
            a1 = fmaf(h0, lo_bf(u1), a1);  c1 = fmaf(h1, hi_bf(u1), c1);
            a2 = fmaf(h0, lo_bf(u2), a2);  c2 = fmaf(h1, hi_bf(u2), c2);
            a3 = fmaf(h0, lo_bf(u3), a3);  c3 = fmaf(h1, hi_bf(u3), c3);
        }
        a0 += c0; a1 += c1; a2 += c2; a3 += c3;
        *(float4*)&parts[ks][jq * 4] = make_float4(a0, a1, a2, a3);
        __syncthreads();                       // barrier B

        // ---- reduce 8 k-slices + bias + x term (tid<256) ----
        if (tid < 256) {
            float g = parts[0][tid] + parts[1][tid] + parts[2][tid] + parts[3][tid]
                    + parts[4][tid] + parts[5][tid] + parts[6][tid] + parts[7][tid]
                    + biasr + xsh[t] * wihr;
            gates[tid] = g;
        }
        __syncthreads();                       // barrier C

        // ---- LSTM cell + STN blend + tagged publish (wave 0: tid<64) ----
        if (tid < UNITS) {
            float ig = sigm(gates[tid]);
            float fg = sigm(gates[64 + tid]);
            float gg = tanh_fast(gates[128 + tid]);
            float og = sigm(gates[192 + tid]);
            float cold = cst[tid], hold = hst[tid];
            float cnew = fg * cold + ig * gg;
            float hnew = og * tanh_fast(cnew);
            float cb = 0.5f * (cold + cnew);
            float hb = 0.5f * (hold + hnew);
            cst[tid] = cb; hst[tid] = hb;
            // single 8B tagged store: data + signal in one coherence leg
            union { float f; unsigned int u; } hv; hv.f = hb;
            unsigned long long pkt =
                ((unsigned long long)(unsigned int)(t + 1) << 32) | hv.u;
            unsigned long long* hout =
                hbuf + ((((t + 1) & 1) * NBATCH + b) << 9) + wg * 64 + tid;
            __hip_atomic_store(hout, pkt, __ATOMIC_RELAXED,
                               __HIP_MEMORY_SCOPE_AGENT);
            if (isbf) outb_u[(size_t)t * NH + wg * 64 + tid] = f2bf_rne(hb);
            else      outb_f[(size_t)t * NH + wg * 64 + tid] = hb;
        }
        // no loop-end barrier: next write before barrier A is hsh[tid],
        // which no thread reads between barrier C and barrier A; gates'
        // next write is after barrier B of t+1 (two barriers downstream).
    }

    // ---- final_state [h | c] ----
    if (tid < UNITS) {
        size_t fsbase = (size_t)NBATCH * NT * NH + (size_t)b * (2 * NH);
        if (isbf) {
            ((unsigned short*)out)[fsbase + wg * 64 + tid]       = f2bf_rne(hst[tid]);
            ((unsigned short*)out)[fsbase + 512 + wg * 64 + tid] = f2bf_rne(cst[tid]);
        } else {
            ((float*)out)[fsbase + wg * 64 + tid]       = hst[tid];
            ((float*)out)[fsbase + 512 + wg * 64 + tid] = cst[tid];
        }
    }
}

extern "C" void kernel_launch(void* const* d_in, const int* in_sizes, int n_in,
                              void* d_out, int out_size, void* d_ws, size_t ws_size,
                              hipStream_t stream) {
    const void* x   = d_in[0];
    const void* Wih = d_in[1];
    const void* Whh = d_in[2];
    const void* bih = d_in[3];
    const void* bhh = d_in[4];

    char* ws = (char*)d_ws;
    int* flagp          = (int*)(ws + FLAG_OFF);
    float* bias_p       = (float*)(ws + BIAS_OFF);
    float* wih_p        = (float*)(ws + WIH_OFF);
    float* Xf           = (float*)(ws + XF_OFF);
    unsigned long long* hbuf = (unsigned long long*)(ws + HBUF_OFF);
    unsigned int* WP    = (unsigned int*)(ws + WP_OFF);

    prep_detect<<<1, 256, 0, stream>>>((const unsigned short*)Wih, flagp);
    prep_conv<<<2048, 256, 0, stream>>>(x, Wih, Whh, bih, bhh, flagp,
                                        WP, bias_p, wih_p, Xf,
                                        (unsigned int*)hbuf);
    rnn_kernel<<<256, 512, 0, stream>>>(Xf, WP, bias_p, wih_p, hbuf,
                                        flagp, d_out);
}